// Round 5
// baseline (247.294 us; speedup 1.0000x reference)
//
#include <hip/hip_runtime.h>

// out = (sum_p cos(w_p * phi_p) + (N - C)) / N,  N = next pow2 >= C.
// Pure memory-bound reduction: 256 MiB read, 4 B write.
// R5: nt loads + 4-deep batch kept; access pattern changed from
// 2048 private 64KB spans (4096 device streams -> HBM row thrash) to a
// device-wide sequential sweep: block reads contiguous 16KB, grid-strides.
// At any instant the device reads ONE marching window per array.
// NOTE: timed dur_us carries ~170 us of harness restore/poison floor.

#define RBLOCKS 2048
#define RTHREADS 256

typedef float v4f __attribute__((ext_vector_type(4)));

__global__ __launch_bounds__(RTHREADS) void qs_partial_kernel(
    const float* __restrict__ phi, const float* __restrict__ w,
    float* __restrict__ partials, int n4, int n) {
    const v4f* __restrict__ p4 = (const v4f*)phi;
    const v4f* __restrict__ w4 = (const v4f*)w;

    const int tid     = (int)threadIdx.x;
    const int gstride = (int)gridDim.x * 4 * RTHREADS;      // device chunk per sweep step
    const int nmain   = (n4 / gstride) * gstride;           // main-loop coverage

    float acc0 = 0.0f, acc1 = 0.0f, acc2 = 0.0f, acc3 = 0.0f;

    // block reads 4 consecutive 1024B wave-tiles (16KB contiguous), then
    // strides by the device footprint: one sequential window per array.
    for (int base = (int)blockIdx.x * (4 * RTHREADS) + tid; base < nmain;
         base += gstride) {
        v4f a0 = __builtin_nontemporal_load(p4 + base);
        v4f a1 = __builtin_nontemporal_load(p4 + base + RTHREADS);
        v4f a2 = __builtin_nontemporal_load(p4 + base + 2 * RTHREADS);
        v4f a3 = __builtin_nontemporal_load(p4 + base + 3 * RTHREADS);
        v4f b0 = __builtin_nontemporal_load(w4 + base);
        v4f b1 = __builtin_nontemporal_load(w4 + base + RTHREADS);
        v4f b2 = __builtin_nontemporal_load(w4 + base + 2 * RTHREADS);
        v4f b3 = __builtin_nontemporal_load(w4 + base + 3 * RTHREADS);
        acc0 += __cosf(a0.x * b0.x) + __cosf(a0.y * b0.y)
              + __cosf(a0.z * b0.z) + __cosf(a0.w * b0.w);
        acc1 += __cosf(a1.x * b1.x) + __cosf(a1.y * b1.y)
              + __cosf(a1.z * b1.z) + __cosf(a1.w * b1.w);
        acc2 += __cosf(a2.x * b2.x) + __cosf(a2.y * b2.y)
              + __cosf(a2.z * b2.z) + __cosf(a2.w * b2.w);
        acc3 += __cosf(a3.x * b3.x) + __cosf(a3.y * b3.y)
              + __cosf(a3.z * b3.z) + __cosf(a3.w * b3.w);
    }
    // tail float4s (n4 not divisible by device chunk): 1-deep grid-stride
    for (int i = nmain + (int)blockIdx.x * RTHREADS + tid; i < n4;
         i += (int)gridDim.x * RTHREADS) {
        v4f a = __builtin_nontemporal_load(p4 + i);
        v4f b = __builtin_nontemporal_load(w4 + i);
        acc0 += __cosf(a.x * b.x) + __cosf(a.y * b.y)
              + __cosf(a.z * b.z) + __cosf(a.w * b.w);
    }
    // scalar tail (n not divisible by 4) — single thread, tiny
    if (blockIdx.x == 0 && threadIdx.x == 0) {
        for (int j = n4 * 4; j < n; ++j) acc0 += __cosf(phi[j] * w[j]);
    }

    float acc = (acc0 + acc1) + (acc2 + acc3);

    // wave-64 shuffle reduce
    #pragma unroll
    for (int off = 32; off > 0; off >>= 1)
        acc += __shfl_down(acc, off, 64);

    __shared__ float smem[RTHREADS / 64];
    int lane = threadIdx.x & 63;
    int wid  = threadIdx.x >> 6;
    if (lane == 0) smem[wid] = acc;
    __syncthreads();
    if (threadIdx.x == 0) {
        float t = 0.0f;
        #pragma unroll
        for (int k = 0; k < RTHREADS / 64; ++k) t += smem[k];
        partials[blockIdx.x] = t;
    }
}

__global__ __launch_bounds__(1024) void qs_final_kernel(
    const float* __restrict__ partials, float* __restrict__ out,
    int nb, float addend, float inv_n) {
    float acc = 0.0f;
    for (int i = threadIdx.x; i < nb; i += blockDim.x) acc += partials[i];

    #pragma unroll
    for (int off = 32; off > 0; off >>= 1)
        acc += __shfl_down(acc, off, 64);

    __shared__ float smem[1024 / 64];
    int lane = threadIdx.x & 63;
    int wid  = threadIdx.x >> 6;
    if (lane == 0) smem[wid] = acc;
    __syncthreads();
    if (threadIdx.x == 0) {
        float t = 0.0f;
        #pragma unroll
        for (int k = 0; k < 1024 / 64; ++k) t += smem[k];
        out[0] = (t + addend) * inv_n;  // overwrites poisoned d_out every call
    }
}

extern "C" void kernel_launch(void* const* d_in, const int* in_sizes, int n_in,
                              void* d_out, int out_size, void* d_ws, size_t ws_size,
                              hipStream_t stream) {
    const float* phi = (const float*)d_in[0];
    const float* w   = (const float*)d_in[1];
    float* out       = (float*)d_out;
    float* partials  = (float*)d_ws;

    int n  = in_sizes[0];
    int n4 = n >> 2;

    // N = 2^ceil(log2(n))
    long long N = 1;
    while (N < (long long)n) N <<= 1;
    float addend = (float)(N - (long long)n);
    float inv_n  = 1.0f / (float)N;

    qs_partial_kernel<<<RBLOCKS, RTHREADS, 0, stream>>>(phi, w, partials, n4, n);
    qs_final_kernel<<<1, 1024, 0, stream>>>(partials, out, RBLOCKS, addend, inv_n);
}